// Round 2
// baseline (11520.816 us; speedup 1.0000x reference)
//
#include <hip/hip_runtime.h>
#include <hip/hip_bf16.h>
#include <initializer_list>

// CSNet: N=16, H=W=256, B=32, csnb=256, BB=1024, F=64
// d_out layout: out[16*1*256*256] | outcsy[16*256*8*8] | out_initrec[16*1*256*256]
// d_ws: A[16,64,256,256] (persistent) + Bt[nc,64,256,256] (temp), storage type
// (fp32/bf16) and chunk count nc chosen at launch from ws_size.

#define HW 65536          // 256*256
#define IMG 4194304       // 64*65536 elems per image for F=64 tensors

// activation storage load/store (compute is always fp32)
__device__ __forceinline__ float ldact(const float* p) { return *p; }
__device__ __forceinline__ float ldact(const __hip_bfloat16* p) { return __bfloat162float(*p); }
__device__ __forceinline__ void  stact(float* p, float v) { *p = v; }
__device__ __forceinline__ void  stact(__hip_bfloat16* p, float v) { *p = __float2bfloat16(v); }

// ---------------- K1: CS sampling conv (stride 32, 32x32 kernel) ----------------
__global__ void k_cs(const float* __restrict__ x, const float* __restrict__ Wcs,
                     float* __restrict__ outcsy)
{
    __shared__ float xs[1024];
    const int bid = blockIdx.x;            // n*64 + hb*8 + wb
    const int wb = bid & 7, hb = (bid >> 3) & 7, n = bid >> 6;
    const int tid = threadIdx.x;
    for (int idx = tid; idx < 1024; idx += 256) {
        int i = idx >> 5, j = idx & 31;
        xs[idx] = x[(long)n * HW + (hb * 32 + i) * 256 + wb * 32 + j];
    }
    __syncthreads();
    const int c = tid;                      // 256 channels
    const float4* W4 = (const float4*)(Wcs + (long)c * 1024);
    float acc = 0.f;
#pragma unroll 4
    for (int k4 = 0; k4 < 256; ++k4) {
        float4 wv = W4[k4];
        acc += wv.x * xs[4 * k4] + wv.y * xs[4 * k4 + 1] +
               wv.z * xs[4 * k4 + 2] + wv.w * xs[4 * k4 + 3];
    }
    outcsy[(long)n * 16384 + c * 64 + hb * 8 + wb] = acc;
}

// ---------------- K2: 1x1 init conv + depth-to-space (reshape_concat) ----------------
__global__ void k_init(const float* __restrict__ outcsy, const float* __restrict__ Winit,
                       float* __restrict__ initrec)
{
    __shared__ float ys[256];
    const int bid = blockIdx.x;
    const int wb = bid & 7, hb = (bid >> 3) & 7, n = bid >> 6;
    const int tid = threadIdx.x;
    ys[tid] = outcsy[(long)n * 16384 + tid * 64 + hb * 8 + wb];
    __syncthreads();
    for (int t = 0; t < 4; ++t) {
        int p = t * 256 + tid;          // p = i*32 + j (row-major for coalesced writes)
        int i = p >> 5, j = p & 31;
        int cc = j * 32 + i;            // source channel
        const float4* W4 = (const float4*)(Winit + (long)cc * 256);
        float acc = 0.f;
#pragma unroll 4
        for (int c4 = 0; c4 < 64; ++c4) {
            float4 wv = W4[c4];
            acc += wv.x * ys[4 * c4] + wv.y * ys[4 * c4 + 1] +
                   wv.z * ys[4 * c4 + 2] + wv.w * ys[4 * c4 + 3];
        }
        initrec[(long)n * HW + (hb * 32 + i) * 256 + wb * 32 + j] = acc;
    }
}

// ---------------- K3: first conv 1->64, 3x3 pad 1, + PReLU ----------------
template <typename T>
__global__ void k_first(const float* __restrict__ initrec, const float* __restrict__ Wf,
                        T* __restrict__ A, const float* __restrict__ alpha_p)
{
    long idx = (long)blockIdx.x * 256 + threadIdx.x;   // [n][co][y][x]
    int x = idx & 255;
    int y = (int)((idx >> 8) & 255);
    int co = (int)((idx >> 16) & 63);                  // wave-uniform -> scalar weight loads
    int n  = (int)(idx >> 22);
    float w[9];
#pragma unroll
    for (int k = 0; k < 9; ++k) w[k] = Wf[co * 9 + k];
    const float* ip = initrec + (long)n * HW;
    float acc = 0.f;
#pragma unroll
    for (int ky = 0; ky < 3; ++ky) {
        int yy = y + ky - 1;
        if ((unsigned)yy < 256u) {
#pragma unroll
            for (int kx = 0; kx < 3; ++kx) {
                int xx = x + kx - 1;
                if ((unsigned)xx < 256u) acc += w[ky * 3 + kx] * ip[yy * 256 + xx];
            }
        }
    }
    float alpha = alpha_p[0];
    stact(&A[idx], (acc >= 0.f) ? acc : alpha * acc);
}

// ---------------- K4: 64->64 3x3 conv, the hot kernel ----------------
// MODE 0: dst = prelu(conv(src))
// MODE 1: dst = prelu(res + conv(src))     (res/dst: same address per-thread only)
// Block: 64 co x (8y x 16x) output tile. LDS: weights [16ci][64co][9] + input [16ci][10][20].
// Pointers are pre-offset to the image chunk; n here is chunk-local.
template <typename T, int MODE>
__global__ __launch_bounds__(256) void k_blk(const T* __restrict__ src,
                                             const T* __restrict__ res,
                                             T* __restrict__ dst,
                                             const float* __restrict__ Wb,
                                             const float* __restrict__ alpha_p)
{
    __shared__ float lds[12416];            // 9216 weights + 3200 input = 49.7 KB
    float* wlds = lds;                      // [(ci*64+co)*9 + k]
    float* ins  = lds + 9216;               // [(ci*10+iy)*20 + ix]

    const int tid = threadIdx.x;
    const int bid = blockIdx.x;
    const int tx = bid & 15;                // 16 x-tiles of 16
    const int ty = (bid >> 4) & 31;         // 32 y-tiles of 8
    const int n  = bid >> 9;                // chunk-local image
    const int x0 = tx * 16, y0 = ty * 8;

    const int co = tid & 63;                // all 64 lanes of a wave share g -> LDS input broadcasts
    const int g  = tid >> 6;                // rows 2g, 2g+1

    float acc[2][16];
#pragma unroll
    for (int o = 0; o < 2; ++o)
#pragma unroll
        for (int xx = 0; xx < 16; ++xx) acc[o][xx] = 0.f;

    for (int c0 = 0; c0 < 64; c0 += 16) {
        // stage weights: global [co][ci][3][3] -> lds [ci][co][9]
        for (int idx = tid; idx < 9216; idx += 256) {
            int k = idx % 9;
            int rest = idx / 9;
            int cco = rest & 63;
            int cci = rest >> 6;
            wlds[idx] = Wb[((long)cco * 64 + c0 + cci) * 9 + k];
        }
        // stage input halo tile: [16][10][18] (row stride padded to 20)
        for (int idx = tid; idx < 2880; idx += 256) {
            int cci = idx / 180;
            int rem = idx - cci * 180;
            int iy = rem / 18;
            int ix = rem - iy * 18;
            int gy = y0 + iy - 1, gx = x0 + ix - 1;
            float v = 0.f;
            if ((unsigned)gy < 256u && (unsigned)gx < 256u)
                v = ldact(&src[(((long)n * 64 + c0 + cci) * 256 + gy) * 256 + gx]);
            ins[(cci * 10 + iy) * 20 + ix] = v;
        }
        __syncthreads();

        for (int ci = 0; ci < 16; ++ci) {
            float w[9];
#pragma unroll
            for (int k = 0; k < 9; ++k) w[k] = wlds[(ci * 64 + co) * 9 + k];
#pragma unroll
            for (int ir = 0; ir < 4; ++ir) {
                float row[18];
                const float* rp = &ins[(ci * 10 + 2 * g + ir) * 20];
#pragma unroll
                for (int t = 0; t < 18; ++t) row[t] = rp[t];
#pragma unroll
                for (int o = 0; o < 2; ++o) {
                    const int ky = ir - o;
                    if (ky >= 0 && ky <= 2) {
#pragma unroll
                        for (int xx = 0; xx < 16; ++xx)
                            acc[o][xx] += w[ky * 3 + 0] * row[xx] +
                                          w[ky * 3 + 1] * row[xx + 1] +
                                          w[ky * 3 + 2] * row[xx + 2];
                    }
                }
            }
        }
        __syncthreads();
    }

    // stage raw conv sums to LDS (alias), then coalesced epilogue
#pragma unroll
    for (int o = 0; o < 2; ++o)
#pragma unroll
        for (int xx = 0; xx < 16; ++xx)
            lds[(co * 8 + 2 * g + o) * 16 + xx] = acc[o][xx];
    __syncthreads();

    const float alpha = alpha_p[0];
    for (int idx = tid; idx < 8192; idx += 256) {
        int cco = idx >> 7;
        int rem = idx & 127;
        int yy = rem >> 4;
        int xx = rem & 15;
        long gaddr = (((long)n * 64 + cco) * 256 + (y0 + yy)) * 256 + (x0 + xx);
        float v = lds[idx];
        if (MODE == 1) v += ldact(&res[gaddr]);
        v = (v >= 0.f) ? v : alpha * v;
        stact(&dst[gaddr], v);
    }
}

// ---------------- K5: last conv (A + initrec_broadcast) -> 1 channel ----------------
template <typename T>
__global__ void k_last(const T* __restrict__ A, const float* __restrict__ initrec,
                       const float* __restrict__ Wl, float* __restrict__ out0)
{
    long idx = (long)blockIdx.x * 256 + threadIdx.x;   // 16*65536
    int x = idx & 255;
    int y = (int)((idx >> 8) & 255);
    int n = (int)(idx >> 16);

    // wsum[k] = sum_ci Wl[ci][k]  (uniform -> scalar regs)
    float wsum[9];
#pragma unroll
    for (int k = 0; k < 9; ++k) wsum[k] = 0.f;
    for (int ci = 0; ci < 64; ++ci)
#pragma unroll
        for (int k = 0; k < 9; ++k) wsum[k] += Wl[ci * 9 + k];

    const T* Ab = A + (long)n * IMG;
    const float* ip = initrec + (long)n * HW;
    float acc = 0.f;
    for (int ci = 0; ci < 64; ++ci) {
#pragma unroll
        for (int ky = 0; ky < 3; ++ky) {
            int yy = y + ky - 1;
            if ((unsigned)yy >= 256u) continue;
#pragma unroll
            for (int kx = 0; kx < 3; ++kx) {
                int xx = x + kx - 1;
                if ((unsigned)xx >= 256u) continue;
                acc += Wl[ci * 9 + ky * 3 + kx] * ldact(&Ab[(long)ci * HW + yy * 256 + xx]);
            }
        }
    }
#pragma unroll
    for (int ky = 0; ky < 3; ++ky) {
        int yy = y + ky - 1;
        if ((unsigned)yy >= 256u) continue;
#pragma unroll
        for (int kx = 0; kx < 3; ++kx) {
            int xx = x + kx - 1;
            if ((unsigned)xx >= 256u) continue;
            acc += wsum[ky * 3 + kx] * ip[yy * 256 + xx];
        }
    }
    out0[idx] = acc;
}

// ---------------- pipeline driver (storage type T, image-chunked temp buffer) ----------------
template <typename T>
static void run_pipeline(const float* initrec_unused, const float* Wf, const float* Wb,
                         const float* Wl, const float* amain, const float* ablk,
                         const float* initrec, float* out0, void* d_ws, int nc,
                         hipStream_t stream)
{
    T* A  = (T*)d_ws;                       // [16,64,256,256]
    T* Bt = A + (size_t)16 * IMG;           // [nc,64,256,256]

    k_first<T><<<262144, 256, 0, stream>>>(initrec, Wf, A, amain);
    for (int i = 0; i < 4; ++i) {
        for (int n0 = 0; n0 < 16; n0 += nc) {
            T* Ac = A + (size_t)n0 * IMG;
            k_blk<T, 0><<<nc * 512, 256, 0, stream>>>(Ac, (const T*)nullptr, Bt, Wb, ablk);
            k_blk<T, 1><<<nc * 512, 256, 0, stream>>>(Bt, Ac, Ac, Wb, ablk);
        }
    }
    k_last<T><<<4096, 256, 0, stream>>>(A, initrec, Wl, out0);
}

extern "C" void kernel_launch(void* const* d_in, const int* in_sizes, int n_in,
                              void* d_out, int out_size, void* d_ws, size_t ws_size,
                              hipStream_t stream)
{
    const float* x     = (const float*)d_in[0];
    const float* Wcs   = (const float*)d_in[1];
    const float* Winit = (const float*)d_in[2];
    const float* Wf    = (const float*)d_in[3];
    const float* Wb    = (const float*)d_in[4];
    const float* Wl    = (const float*)d_in[5];
    const float* amain = (const float*)d_in[6];
    const float* ablk  = (const float*)d_in[7];

    float* out0    = (float*)d_out;
    float* outcsy  = out0 + 1048576;           // 16*256*8*8
    float* initrec = outcsy + 262144;          // 16*1*256*256

    k_cs<<<1024, 256, 0, stream>>>(x, Wcs, outcsy);
    k_init<<<1024, 256, 0, stream>>>(outcsy, Winit, initrec);

    // choose storage type + temp-buffer image-chunk count from ws_size
    const size_t AE = (size_t)16 * IMG;        // persistent activation elems
    int nc32 = 0, nc16 = 0;
    for (int c : {16, 8, 4, 2, 1}) { if ((AE + (size_t)c * IMG) * 4 <= ws_size) { nc32 = c; break; } }
    for (int c : {16, 8, 4, 2, 1}) { if ((AE + (size_t)c * IMG) * 2 <= ws_size) { nc16 = c; break; } }

    if (nc32 >= 2) {
        run_pipeline<float>(nullptr, Wf, Wb, Wl, amain, ablk, initrec, out0, d_ws, nc32, stream);
    } else if (nc16 >= 1) {
        run_pipeline<__hip_bfloat16>(nullptr, Wf, Wb, Wl, amain, ablk, initrec, out0, d_ws, nc16, stream);
    } else {
        // ws too small for any valid plan; attempt minimal bf16 (documents the constraint)
        run_pipeline<__hip_bfloat16>(nullptr, Wf, Wb, Wl, amain, ablk, initrec, out0, d_ws, 1, stream);
    }
}

// Round 3
// 1418.350 us; speedup vs baseline: 8.1227x; 8.1227x over previous
//
#include <hip/hip_runtime.h>
#include <hip/hip_bf16.h>
#include <initializer_list>

// CSNet on MI355X — round 3: bf16 MFMA implicit-GEMM for the 64->64 3x3 convs.
// Activations NHWC bf16: act[n][y][x][c=64], pixel = 128 B.
// d_out: out[16*65536] | outcsy[16*16384] | initrec[16*65536]  (all fp32)
// d_ws:  A[16 img] bf16 NHWC | Bt[nc img] bf16 NHWC | Wprep[36864] bf16

#define HW 65536
#define IMG 4194304        // 64*HW elems per image

typedef __attribute__((ext_vector_type(8))) short short8;
typedef __attribute__((ext_vector_type(4))) float f32x4;

__device__ __forceinline__ float bf2f(unsigned short u) {
    union { unsigned u; float f; } v; v.u = ((unsigned)u) << 16; return v.f;
}
__device__ __forceinline__ unsigned short f2bf(float f) {
    union { float f; unsigned u; } v; v.f = f;
    unsigned r = v.u + 0x7FFF + ((v.u >> 16) & 1);   // RNE
    return (unsigned short)(r >> 16);
}

// ---------------- K1: CS sampling conv (stride 32, 32x32 kernel) ----------------
__global__ void k_cs(const float* __restrict__ x, const float* __restrict__ Wcs,
                     float* __restrict__ outcsy)
{
    __shared__ float xs[1024];
    const int bid = blockIdx.x;            // n*64 + hb*8 + wb
    const int wb = bid & 7, hb = (bid >> 3) & 7, n = bid >> 6;
    const int tid = threadIdx.x;
    for (int idx = tid; idx < 1024; idx += 256) {
        int i = idx >> 5, j = idx & 31;
        xs[idx] = x[(long)n * HW + (hb * 32 + i) * 256 + wb * 32 + j];
    }
    __syncthreads();
    const int c = tid;
    const float4* W4 = (const float4*)(Wcs + (long)c * 1024);
    float acc = 0.f;
#pragma unroll 4
    for (int k4 = 0; k4 < 256; ++k4) {
        float4 wv = W4[k4];
        acc += wv.x * xs[4 * k4] + wv.y * xs[4 * k4 + 1] +
               wv.z * xs[4 * k4 + 2] + wv.w * xs[4 * k4 + 3];
    }
    outcsy[(long)n * 16384 + c * 64 + hb * 8 + wb] = acc;
}

// ---------------- K2: 1x1 init conv + depth-to-space ----------------
__global__ void k_init(const float* __restrict__ outcsy, const float* __restrict__ Winit,
                       float* __restrict__ initrec)
{
    __shared__ float ys[256];
    const int bid = blockIdx.x;
    const int wb = bid & 7, hb = (bid >> 3) & 7, n = bid >> 6;
    const int tid = threadIdx.x;
    ys[tid] = outcsy[(long)n * 16384 + tid * 64 + hb * 8 + wb];
    __syncthreads();
    for (int t = 0; t < 4; ++t) {
        int p = t * 256 + tid;          // p = i*32 + j
        int i = p >> 5, j = p & 31;
        int cc = j * 32 + i;
        const float4* W4 = (const float4*)(Winit + (long)cc * 256);
        float acc = 0.f;
#pragma unroll 4
        for (int c4 = 0; c4 < 64; ++c4) {
            float4 wv = W4[c4];
            acc += wv.x * ys[4 * c4] + wv.y * ys[4 * c4 + 1] +
                   wv.z * ys[4 * c4 + 2] + wv.w * ys[4 * c4 + 3];
        }
        initrec[(long)n * HW + (hb * 32 + i) * 256 + wb * 32 + j] = acc;
    }
}

// ---------------- K3: first conv 1->64 + PReLU, NHWC bf16 out ----------------
__global__ __launch_bounds__(256) void k_first(const float* __restrict__ initrec,
        const float* __restrict__ Wf, unsigned short* __restrict__ A,
        const float* __restrict__ alpha_p)
{
    const int tid = threadIdx.x;
    const int w = tid >> 6, lane = tid & 63;
    const long p0 = (long)blockIdx.x * 64 + w * 16;   // 16 consecutive x, same row
    const int n = (int)(p0 >> 16);
    const int y = (int)((p0 >> 8) & 255);
    const int xb = (int)(p0 & 255);
    float wf[9];
#pragma unroll
    for (int k = 0; k < 9; ++k) wf[k] = Wf[lane * 9 + k];
    const float alpha = alpha_p[0];
    const float* ip = initrec + (long)n * HW;
    for (int i = 0; i < 16; ++i) {
        int x = xb + i;
        float acc = 0.f;
#pragma unroll
        for (int ky = 0; ky < 3; ++ky) {
            int yy = y + ky - 1;
            if ((unsigned)yy >= 256u) continue;
#pragma unroll
            for (int kx = 0; kx < 3; ++kx) {
                int xx = x + kx - 1;
                if ((unsigned)xx >= 256u) continue;
                acc += wf[ky * 3 + kx] * ip[yy * 256 + xx];
            }
        }
        acc = acc >= 0.f ? acc : alpha * acc;
        A[(p0 + i) * 64 + lane] = f2bf(acc);
    }
}

// ---------------- weight prep: fp32 [co][ci][3][3] -> bf16 B-fragment order ----------------
// Wp[cc][tap][nt][lane][j] = W[co=nt*16+(lane&15)][ci=cc*32+(lane>>4)*8+j][tap]
__global__ void k_wprep(const float* __restrict__ Wb, unsigned short* __restrict__ Wp)
{
    int e = blockIdx.x * 256 + threadIdx.x;   // 36864 total
    int cc = e / 18432, r = e % 18432;
    int tap = r / 2048, r2 = r % 2048;
    int nt = (r2 >> 9) & 3, l = (r2 >> 3) & 63, j = r2 & 7;
    int co = nt * 16 + (l & 15);
    int ci = cc * 32 + (l >> 4) * 8 + j;
    Wp[e] = f2bf(Wb[co * 576 + ci * 9 + tap]);
}

// ---------------- K4: 64->64 3x3 conv via MFMA, NHWC bf16 ----------------
// MODE 0: dst = prelu(conv(src));  MODE 1: dst = prelu(res + conv(src))
// wg = 4 waves; tile 16y x 16x x 64co. Wave w: rows 4w..4w+3 (4 M-tiles of 16 x-pos).
template <int MODE>
__global__ __launch_bounds__(256) void k_conv(const unsigned short* __restrict__ src,
        const unsigned short* __restrict__ res, unsigned short* __restrict__ dst,
        const unsigned short* __restrict__ Wp, const float* __restrict__ alpha_p)
{
    __shared__ short wls[18432];   // 36.9 KB: B-frags for one ci-chunk (9 taps x 4 nt x 64 x 8)
    __shared__ short ibuf[12960];  // 25.9 KB: halo 18x18 px x 32 ci, pixel stride 40 shorts (80 B)

    const int tid = threadIdx.x;
    const int bid = blockIdx.x;
    const int tx = bid & 15, ty = (bid >> 4) & 15, n = bid >> 8;  // n chunk-local
    const int x0 = tx * 16, y0 = ty * 16;
    const int w = tid >> 6, lane = tid & 63;
    const int q = lane >> 4, mm = lane & 15;

    const f32x4 zz = {0.f, 0.f, 0.f, 0.f};
    f32x4 acc[4][4];
#pragma unroll
    for (int mt = 0; mt < 4; ++mt)
#pragma unroll
        for (int nt = 0; nt < 4; ++nt) acc[mt][nt] = zz;

    const unsigned short* sb = src + (long)n * IMG;

    for (int cc = 0; cc < 2; ++cc) {
        // stage weights (straight copy, already fragment-ordered)
#pragma unroll
        for (int i = 0; i < 9; ++i) {
            int s16 = tid + 256 * i;          // 2304 chunks of 16 B
            *(short8*)&wls[s16 * 8] = *(const short8*)&Wp[(size_t)cc * 18432 + s16 * 8];
        }
        // stage input halo (18x18 px, 32 ci of this chunk, zero-pad boundary)
        for (int i = 0; i < 6; ++i) {
            int idx = tid + 256 * i;          // 1296 chunks of 16 B
            if (idx < 1296) {
                int pix = idx >> 2, part = idx & 3;
                int row = pix / 18, col = pix - row * 18;
                int gy = y0 + row - 1, gx = x0 + col - 1;
                short8 v = {0, 0, 0, 0, 0, 0, 0, 0};
                if ((unsigned)gy < 256u && (unsigned)gx < 256u)
                    v = *(const short8*)&sb[((long)gy * 256 + gx) * 64 + cc * 32 + part * 8];
                *(short8*)&ibuf[pix * 40 + part * 8] = v;
            }
        }
        __syncthreads();

        for (int tap = 0; tap < 9; ++tap) {
            const int ky = tap / 3, kx = tap - ky * 3;
            short8 bf[4];
#pragma unroll
            for (int nt = 0; nt < 4; ++nt)
                bf[nt] = *(const short8*)&wls[((tap * 4 + nt) * 64 + lane) * 8];
#pragma unroll
            for (int mt = 0; mt < 4; ++mt) {
                const int ri = 4 * w + mt + ky;      // halo row
                const int cl = mm + kx;              // halo col (per-lane m)
                short8 af = *(const short8*)&ibuf[(ri * 18 + cl) * 40 + q * 8];
#pragma unroll
                for (int nt = 0; nt < 4; ++nt)
                    acc[mt][nt] = __builtin_amdgcn_mfma_f32_16x16x32_bf16(
                        af, bf[nt], acc[mt][nt], 0, 0, 0);
            }
        }
        __syncthreads();
    }

    // epilogue: acc -> LDS (tile NHWC order), then coalesced global stores
    unsigned short* ob = (unsigned short*)wls;       // 32 KB needed, fits in wls
#pragma unroll
    for (int mt = 0; mt < 4; ++mt) {
        int row = 4 * w + mt;
#pragma unroll
        for (int nt = 0; nt < 4; ++nt) {
#pragma unroll
            for (int r = 0; r < 4; ++r) {
                int xx = q * 4 + r;                  // D row = (lane>>4)*4 + reg = x pos
                ob[(row * 16 + xx) * 64 + nt * 16 + mm] = f2bf(acc[mt][nt][r]);
            }
        }
    }
    __syncthreads();

    const float alpha = alpha_p[0];
    for (int i = 0; i < 8; ++i) {
        int s16 = tid + 256 * i;                     // 2048 chunks of 8 shorts
        int e = s16 * 8;
        int co = e & 63, xx = (e >> 6) & 15, row = e >> 10;
        long g = (((long)n * 256 + y0 + row) * 256 + (x0 + xx)) * 64 + co;
        short8 cv = *(short8*)&ob[e];
        short8 rv = {0, 0, 0, 0, 0, 0, 0, 0};
        if (MODE == 1) rv = *(const short8*)&res[g];
        short8 ov;
#pragma unroll
        for (int j = 0; j < 8; ++j) {
            float v = bf2f((unsigned short)cv[j]);
            if (MODE == 1) v += bf2f((unsigned short)rv[j]);
            v = (v >= 0.f) ? v : alpha * v;
            ov[j] = (short)f2bf(v);
        }
        *(short8*)&dst[g] = ov;
    }
}

// ---------------- K5: last conv (A + initrec) -> 1 channel, NHWC in ----------------
__global__ __launch_bounds__(256) void k_last(const unsigned short* __restrict__ A,
        const float* __restrict__ initrec, const float* __restrict__ Wl,
        float* __restrict__ out0)
{
    const int bid = blockIdx.x;          // n*256 + y
    const int y = bid & 255, n = bid >> 8;
    const int x = threadIdx.x;
    const unsigned short* Ab = A + (long)n * IMG;
    const float* ip = initrec + (long)n * HW;

    float acc = 0.f;
#pragma unroll
    for (int ky = 0; ky < 3; ++ky) {
        int yy = y + ky - 1;
        if ((unsigned)yy >= 256u) continue;
#pragma unroll
        for (int kx = 0; kx < 3; ++kx) {
            int xx = x + kx - 1;
            if ((unsigned)xx >= 256u) continue;
            int tap = ky * 3 + kx;
            const unsigned short* ap = &Ab[((long)yy * 256 + xx) * 64];
            for (int c8 = 0; c8 < 8; ++c8) {
                short8 av = *(const short8*)&ap[c8 * 8];
#pragma unroll
                for (int j = 0; j < 8; ++j)
                    acc += Wl[(c8 * 8 + j) * 9 + tap] * bf2f((unsigned short)av[j]);
            }
            // initrec contribution uses summed weight over ci
            float ws = 0.f;
            for (int ci = 0; ci < 64; ++ci) ws += Wl[ci * 9 + tap];
            acc += ws * ip[yy * 256 + xx];
        }
    }
    out0[(long)bid * 256 + x] = acc;
}

extern "C" void kernel_launch(void* const* d_in, const int* in_sizes, int n_in,
                              void* d_out, int out_size, void* d_ws, size_t ws_size,
                              hipStream_t stream)
{
    const float* x     = (const float*)d_in[0];
    const float* Wcs   = (const float*)d_in[1];
    const float* Winit = (const float*)d_in[2];
    const float* Wf    = (const float*)d_in[3];
    const float* Wb    = (const float*)d_in[4];
    const float* Wl    = (const float*)d_in[5];
    const float* amain = (const float*)d_in[6];
    const float* ablk  = (const float*)d_in[7];

    float* out0    = (float*)d_out;
    float* outcsy  = out0 + 1048576;
    float* initrec = outcsy + 262144;

    unsigned short* A = (unsigned short*)d_ws;        // [16] img bf16 NHWC
    int nc = 1;
    for (int c : {16, 8, 4, 2, 1})
        if ((size_t)(16 + c) * IMG * 2 + 73728 <= ws_size) { nc = c; break; }
    unsigned short* Bt = A + (size_t)16 * IMG;        // [nc] img temp
    unsigned short* Wp = Bt + (size_t)nc * IMG;       // 36864 bf16

    k_cs<<<1024, 256, 0, stream>>>(x, Wcs, outcsy);
    k_init<<<1024, 256, 0, stream>>>(outcsy, Winit, initrec);
    k_wprep<<<144, 256, 0, stream>>>(Wb, Wp);
    k_first<<<16384, 256, 0, stream>>>(initrec, Wf, A, amain);

    for (int i = 0; i < 4; ++i) {
        for (int n0 = 0; n0 < 16; n0 += nc) {
            unsigned short* Ac = A + (size_t)n0 * IMG;
            k_conv<0><<<nc * 256, 256, 0, stream>>>(Ac, (const unsigned short*)nullptr,
                                                    Bt, Wp, ablk);
            k_conv<1><<<nc * 256, 256, 0, stream>>>(Bt, Ac, Ac, Wp, ablk);
        }
    }
    k_last<<<4096, 256, 0, stream>>>(A, initrec, Wl, out0);
}